// Round 1
// baseline (1376.251 us; speedup 1.0000x reference)
//
#include <hip/hip_runtime.h>

#define N_NODES 65536
#define N_EDGES 524288
#define C_IN 128
#define H_DIM 512
#define CH_DIM 256
#define BS 512

// ---------------- degree / norm ----------------
__global__ void deg_init_k(float* __restrict__ deg) {
    int i = blockIdx.x * 256 + threadIdx.x;
    deg[i] = 1.0f;  // self-loop weight
}
__global__ void deg_acc_k(const int* __restrict__ dst, const float* __restrict__ w,
                          float* __restrict__ deg) {
    int i = blockIdx.x * 256 + threadIdx.x;
    atomicAdd(&deg[dst[i]], w[i]);
}
__global__ void deg_fin_k(float* __restrict__ deg) {
    int i = blockIdx.x * 256 + threadIdx.x;
    deg[i] = rsqrtf(deg[i]);  // deg >= 1 always (self-loop)
}

// ---------------- W_comb = w1_gcn2 @ w_gcn, stored transposed (f, c) ----------------
__global__ void wcomb_k(const float* __restrict__ w1, const float* __restrict__ wg,
                        float* __restrict__ WT) {
    int t = blockIdx.x * 256 + threadIdx.x;  // 512*128
    int f = t >> 7, c = t & 127;
    float s = 0.f;
#pragma unroll 8
    for (int m = 0; m < 128; ++m) s += w1[c * 128 + m] * wg[m * 512 + f];
    WT[t] = s;  // WT[f*128 + c]
}

// ---------------- y = P x  (propagate on 128-dim input) ----------------
__global__ void y_init_k(const float* __restrict__ x, const float* __restrict__ dinv,
                         float* __restrict__ y) {
    int t = blockIdx.x * 256 + threadIdx.x;  // N*32 threads, float4 each
    int node = t >> 5, c4 = (t & 31) * 4;
    float s = dinv[node];
    s = s * s;  // self-loop norm
    float4 v = *(const float4*)(x + (size_t)node * 128 + c4);
    v.x *= s; v.y *= s; v.z *= s; v.w *= s;
    *(float4*)(y + (size_t)node * 128 + c4) = v;
}
__global__ void y_edge_k(const int* __restrict__ src, const int* __restrict__ dst,
                         const float* __restrict__ w, const float* __restrict__ dinv,
                         const float* __restrict__ x, float* __restrict__ y) {
    int t = blockIdx.x * 256 + threadIdx.x;  // E*64 threads, 2 channels each
    int e = t >> 6;
    int c2 = (t & 63) * 2;
    int s = src[e], d = dst[e];
    float coef = dinv[s] * w[e] * dinv[d];
    float2 v = *(const float2*)(x + (size_t)s * 128 + c2);
    atomicAdd(&y[(size_t)d * 128 + c2], coef * v.x);
    atomicAdd(&y[(size_t)d * 128 + c2 + 1], coef * v.y);
}

// ---------------- generic tiled fp32 GEMM: C = act(A @ B^T + bias) ----------------
// A: M x K row-major.  B: N x K row-major (i.e. weights in (out,in) layout).
// ACT: 0 none, 1 relu, 2 tanh.  PERM: store with the rearrange permutation
// (row m is a node index; stored at V[(b*32+e), g*512 + n]).
template <int ACT, bool PERM>
__global__ __launch_bounds__(256) void gemm_abt_k(
    const float* __restrict__ A, const float* __restrict__ B,
    const float* __restrict__ bias, float* __restrict__ C,
    int M, int N, int K) {
    __shared__ float As[32][65];
    __shared__ float Bs[32][65];
    const int bm = blockIdx.y * 64, bn = blockIdx.x * 64;
    const int tid = threadIdx.x;
    const int tx = tid & 15, ty = tid >> 4;
    const int r = tid >> 3, c4 = (tid & 7) * 4;
    float acc[4][4] = {};

    for (int kt = 0; kt < K; kt += 32) {
        float4 a0 = *(const float4*)(A + (size_t)(bm + r) * K + kt + c4);
        float4 a1 = *(const float4*)(A + (size_t)(bm + r + 32) * K + kt + c4);
        float4 b0 = *(const float4*)(B + (size_t)(bn + r) * K + kt + c4);
        float4 b1 = *(const float4*)(B + (size_t)(bn + r + 32) * K + kt + c4);
        As[c4 + 0][r] = a0.x; As[c4 + 1][r] = a0.y; As[c4 + 2][r] = a0.z; As[c4 + 3][r] = a0.w;
        As[c4 + 0][r + 32] = a1.x; As[c4 + 1][r + 32] = a1.y; As[c4 + 2][r + 32] = a1.z; As[c4 + 3][r + 32] = a1.w;
        Bs[c4 + 0][r] = b0.x; Bs[c4 + 1][r] = b0.y; Bs[c4 + 2][r] = b0.z; Bs[c4 + 3][r] = b0.w;
        Bs[c4 + 0][r + 32] = b1.x; Bs[c4 + 1][r + 32] = b1.y; Bs[c4 + 2][r + 32] = b1.z; Bs[c4 + 3][r + 32] = b1.w;
        __syncthreads();
#pragma unroll
        for (int k = 0; k < 32; ++k) {
            float av[4], bv[4];
#pragma unroll
            for (int i = 0; i < 4; ++i) av[i] = As[k][ty * 4 + i];
#pragma unroll
            for (int j = 0; j < 4; ++j) bv[j] = Bs[k][tx * 4 + j];
#pragma unroll
            for (int i = 0; i < 4; ++i)
#pragma unroll
                for (int j = 0; j < 4; ++j) acc[i][j] += av[i] * bv[j];
        }
        __syncthreads();
    }

#pragma unroll
    for (int i = 0; i < 4; ++i) {
#pragma unroll
        for (int j = 0; j < 4; ++j) {
            int m = bm + ty * 4 + i;
            int nn = bn + tx * 4 + j;
            float v = acc[i][j] + bias[nn];
            if (ACT == 1) v = fmaxf(v, 0.f);
            if (ACT == 2) v = tanhf(v);
            size_t idx;
            if (PERM) {
                // m = node = b*128 + g*32 + e ; store V[(b*32+e) , g*512 + nn]
                size_t row = (size_t)(((m >> 7) << 5) | (m & 31));
                idx = row * 2048 + (size_t)(((m >> 5) & 3) * 512 + nn);
            } else {
                idx = (size_t)m * N + nn;
            }
            C[idx] = v;
        }
    }
}

// ---------------- final: out[b] = sigmoid(sum act2[(b*32+e), p] * wlin[p*32+e] + blin) ----
__global__ __launch_bounds__(256) void final_k(const float* __restrict__ act2,
                                               const float* __restrict__ wlin,
                                               const float* __restrict__ blin,
                                               float* __restrict__ out) {
    int b = blockIdx.x;
    int t = threadIdx.x;  // p = t in [0,256)
    float s = 0.f;
#pragma unroll 8
    for (int e = 0; e < 32; ++e)
        s += act2[((size_t)(b * 32 + e)) * 256 + t] * wlin[t * 32 + e];
#pragma unroll
    for (int off = 32; off > 0; off >>= 1) s += __shfl_down(s, off, 64);
    __shared__ float partial[4];
    if ((t & 63) == 0) partial[t >> 6] = s;
    __syncthreads();
    if (t == 0) {
        float tot = partial[0] + partial[1] + partial[2] + partial[3] + blin[0];
        out[b] = 1.f / (1.f + expf(-tot));
    }
}

extern "C" void kernel_launch(void* const* d_in, const int* in_sizes, int n_in,
                              void* d_out, int out_size, void* d_ws, size_t ws_size,
                              hipStream_t stream) {
    const float* x    = (const float*)d_in[0];
    const float* eattr= (const float*)d_in[1];
    const float* w1   = (const float*)d_in[2];
    const float* wg   = (const float*)d_in[3];
    const float* bg   = (const float*)d_in[4];
    const float* wc1  = (const float*)d_in[5];
    const float* bc1  = (const float*)d_in[6];
    const float* wc2  = (const float*)d_in[7];
    const float* bc2  = (const float*)d_in[8];
    const float* wlin = (const float*)d_in[9];
    const float* blin = (const float*)d_in[10];
    const int*   ei   = (const int*)d_in[11];
    const int* esrc = ei;
    const int* edst = ei + N_EDGES;
    float* out = (float*)d_out;

    // workspace layout (floats)
    float* ws   = (float*)d_ws;
    float* dinv = ws;                                // 65536
    float* WT   = ws + 65536;                        // 65536  (W_comb^T: [f][c])
    float* y    = ws + 131072;                       // 65536*128 = 8388608
    float* V    = ws + 131072 + 8388608;             // 16384*2048 = 33554432
    float* act1 = y;   // reuse: y dead after h2 GEMM (16384*512 = 8388608 fits)
    float* act2 = V;   // reuse: V dead after GEMM1  (16384*256 fits)

    size_t need_bytes = (size_t)(65536 + 65536 + 8388608 + 33554432) * 4;
    if (ws_size < need_bytes) return;  // fail visibly rather than corrupt

    // 1) gcn_norm
    deg_init_k<<<N_NODES / 256, 256, 0, stream>>>(dinv);
    deg_acc_k<<<N_EDGES / 256, 256, 0, stream>>>(edst, eattr, dinv);
    deg_fin_k<<<N_NODES / 256, 256, 0, stream>>>(dinv);

    // 2) W_comb^T = (w1_gcn2 @ w_gcn)^T
    wcomb_k<<<(512 * 128) / 256, 256, 0, stream>>>(w1, wg, WT);

    // 3) y = P x  (SpMM on 128-dim features)
    y_init_k<<<(N_NODES * 32) / 256, 256, 0, stream>>>(x, dinv, y);
    y_edge_k<<<(N_EDGES * 64) / 256, 256, 0, stream>>>(esrc, edst, eattr, dinv, x, y);

    // 4) h2 = tanh(y @ W_comb + b_gcn), stored in rearranged V layout
    gemm_abt_k<2, true><<<dim3(512 / 64, 65536 / 64), 256, 0, stream>>>(
        y, WT, bg, V, 65536, 512, 128);

    // 5) cnn1: act1 = relu(V @ wc1^T + bc1)   (16384 x 2048) x (512 x 2048)^T
    gemm_abt_k<1, false><<<dim3(512 / 64, 16384 / 64), 256, 0, stream>>>(
        V, wc1, bc1, act1, 16384, 512, 2048);

    // 6) cnn2: act2 = relu(act1 @ wc2^T + bc2)  (16384 x 512) x (256 x 512)^T
    gemm_abt_k<1, false><<<dim3(256 / 64, 16384 / 64), 256, 0, stream>>>(
        act1, wc2, bc2, act2, 16384, 256, 512);

    // 7) final linear + sigmoid
    final_k<<<BS, 256, 0, stream>>>(act2, wlin, blin, out);
}

// Round 2
// 625.371 us; speedup vs baseline: 2.2007x; 2.2007x over previous
//
#include <hip/hip_runtime.h>
#include <hip/hip_bf16.h>

#define N_NODES 65536
#define N_EDGES 524288
#define BS 512

typedef __attribute__((ext_vector_type(8))) short bf16x8;
typedef __attribute__((ext_vector_type(4))) float f32x4;

// ---------------- degree / norm ----------------
__global__ void deg_init_k(float* __restrict__ deg) {
    int i = blockIdx.x * 256 + threadIdx.x;
    deg[i] = 1.0f;  // self-loop weight
}
__global__ void deg_acc_k(const int* __restrict__ dst, const float* __restrict__ w,
                          float* __restrict__ deg) {
    int i = blockIdx.x * 256 + threadIdx.x;
    atomicAdd(&deg[dst[i]], w[i]);
}
__global__ void deg_fin_k(float* __restrict__ deg) {
    int i = blockIdx.x * 256 + threadIdx.x;
    deg[i] = rsqrtf(deg[i]);
}

// ---------------- W_comb^T = (w1_gcn2 @ w_gcn)^T in bf16, layout [f][c] -------
__global__ void wcomb_k(const float* __restrict__ w1, const float* __restrict__ wg,
                        __hip_bfloat16* __restrict__ WT) {
    int t = blockIdx.x * 256 + threadIdx.x;  // 512*128
    int f = t >> 7, c = t & 127;
    float s = 0.f;
#pragma unroll 8
    for (int m = 0; m < 128; ++m) s += w1[c * 128 + m] * wg[m * 512 + f];
    WT[t] = __float2bfloat16(s);
}

// ---------------- y = P x (propagate on 128-dim input, fp32 atomics) ----------
__global__ void y_init_k(const float* __restrict__ x, const float* __restrict__ dinv,
                         float* __restrict__ y) {
    int t = blockIdx.x * 256 + threadIdx.x;
    int node = t >> 5, c4 = (t & 31) * 4;
    float s = dinv[node];
    s = s * s;
    float4 v = *(const float4*)(x + (size_t)node * 128 + c4);
    v.x *= s; v.y *= s; v.z *= s; v.w *= s;
    *(float4*)(y + (size_t)node * 128 + c4) = v;
}
__global__ void y_edge_k(const int* __restrict__ src, const int* __restrict__ dst,
                         const float* __restrict__ w, const float* __restrict__ dinv,
                         const float* __restrict__ x, float* __restrict__ y) {
    int t = blockIdx.x * 256 + threadIdx.x;  // E*64 threads, 2 channels each
    int e = t >> 6;
    int c2 = (t & 63) * 2;
    int s = src[e], d = dst[e];
    float coef = dinv[s] * w[e] * dinv[d];
    float2 v = *(const float2*)(x + (size_t)s * 128 + c2);
    atomicAdd(&y[(size_t)d * 128 + c2], coef * v.x);
    atomicAdd(&y[(size_t)d * 128 + c2 + 1], coef * v.y);
}

// ---------------- fp32 -> bf16 vectorized conversion --------------------------
__global__ void f2b_k(const float* __restrict__ in, __hip_bfloat16* __restrict__ out) {
    int i = (blockIdx.x * 256 + threadIdx.x) * 4;
    float4 v = *(const float4*)(in + i);
    alignas(8) __hip_bfloat16 tmp[4] = {__float2bfloat16(v.x), __float2bfloat16(v.y),
                                        __float2bfloat16(v.z), __float2bfloat16(v.w)};
    *(ushort4*)((unsigned short*)out + i) = *(const ushort4*)tmp;
}

// ---------------- async global -> LDS, 16B per lane ---------------------------
__device__ __forceinline__ void gll16(const void* g, void* l) {
    __builtin_amdgcn_global_load_lds(
        (const __attribute__((address_space(1))) void*)g,
        (__attribute__((address_space(3))) void*)l, 16, 0, 0);
}

// ---------------- bf16 MFMA GEMM: C = act(A @ B^T + bias) ---------------------
// A: M x K bf16 row-major. B: N x K bf16 row-major ((out,in) weights).
// ACT: 0 none, 1 relu, 2 tanh.
// OUT_MODE: 0 fp32 row-major, 1 bf16 row-major, 2 bf16 with rearrange-permute.
// 128x128 tile, BK=32, 4 waves (2x2), each wave 64x64 via 4x4 16x16x32 frags.
template <int ACT, int OUT_MODE>
__global__ __launch_bounds__(256) void gemm_mfma_k(
    const __hip_bfloat16* __restrict__ A, const __hip_bfloat16* __restrict__ B,
    const float* __restrict__ bias, void* __restrict__ Cout,
    int M, int N, int K) {
    __shared__ char lds[16384];  // A tile 8KB | B tile 8KB
    char* ldsA = lds;
    char* ldsB = lds + 8192;

    const int tid = threadIdx.x;
    const int lane = tid & 63, wid = tid >> 6;
    const int bm = blockIdx.y * 128, bn = blockIdx.x * 128;
    const int wr = wid >> 1, wc = wid & 1;

    // staging coords: per wave-chunk, 16 rows x 32 cols (1KB)
    const int srow = wid * 16 + (lane >> 2);     // row within 64-row chunk
    const int skcol = (lane & 3) * 8;            // k element offset
    const __hip_bfloat16* Abase = A + (size_t)(bm + srow) * K + skcol;
    const __hip_bfloat16* Bbase = B + (size_t)(bn + srow) * K + skcol;
    const int ldso = wid * 1024 + (lane & 63) * 0;  // wave-uniform LDS base

    f32x4 acc[4][4] = {};

    const int lrow = lane & 15;
    const int lkb = (lane >> 4) * 16;  // byte offset of k-slice in a 64B row

    for (int kt = 0; kt < K; kt += 32) {
        gll16(Abase + kt,                     ldsA + ldso);
        gll16(Abase + kt + (size_t)64 * K,    ldsA + 4096 + ldso);
        gll16(Bbase + kt,                     ldsB + ldso);
        gll16(Bbase + kt + (size_t)64 * K,    ldsB + 4096 + ldso);
        __syncthreads();  // compiler drains vmcnt(0) before s_barrier

        bf16x8 af[4], bfr[4];
#pragma unroll
        for (int i = 0; i < 4; ++i)
            af[i] = *(const bf16x8*)(ldsA + (wr * 64 + i * 16 + lrow) * 64 + lkb);
#pragma unroll
        for (int j = 0; j < 4; ++j)
            bfr[j] = *(const bf16x8*)(ldsB + (wc * 64 + j * 16 + lrow) * 64 + lkb);
#pragma unroll
        for (int i = 0; i < 4; ++i)
#pragma unroll
            for (int j = 0; j < 4; ++j)
                acc[i][j] = __builtin_amdgcn_mfma_f32_16x16x32_bf16(
                    af[i], bfr[j], acc[i][j], 0, 0, 0);
        __syncthreads();
    }

    // epilogue: C/D layout col=lane&15, row=(lane>>4)*4+reg
    const int crow0 = wr * 64 + (lane >> 4) * 4;
    const int ccol0 = wc * 64 + (lane & 15);
#pragma unroll
    for (int i = 0; i < 4; ++i) {
#pragma unroll
        for (int j = 0; j < 4; ++j) {
            int col = bn + ccol0 + j * 16;
            float bv = bias[col];
#pragma unroll
            for (int r = 0; r < 4; ++r) {
                int row = bm + crow0 + i * 16 + r;
                float v = acc[i][j][r] + bv;
                if (ACT == 1) v = fmaxf(v, 0.f);
                if (ACT == 2) v = tanhf(v);
                if (OUT_MODE == 0) {
                    ((float*)Cout)[(size_t)row * N + col] = v;
                } else if (OUT_MODE == 1) {
                    ((__hip_bfloat16*)Cout)[(size_t)row * N + col] = __float2bfloat16(v);
                } else {
                    // row = node = b*128 + g*32 + e ; store V[(b*32+e), g*512 + col]
                    size_t prow = (size_t)(((row >> 7) << 5) | (row & 31));
                    size_t idx = prow * 2048 + (size_t)(((row >> 5) & 3) * 512 + col);
                    ((__hip_bfloat16*)Cout)[idx] = __float2bfloat16(v);
                }
            }
        }
    }
}

// ---------------- final: out[b] = sigmoid(sum act2[(b*32+e), p] * wlin[p*32+e]) ----
__global__ __launch_bounds__(256) void final_k(const float* __restrict__ act2,
                                               const float* __restrict__ wlin,
                                               const float* __restrict__ blin,
                                               float* __restrict__ out) {
    int b = blockIdx.x;
    int t = threadIdx.x;  // p = t in [0,256)
    float s = 0.f;
#pragma unroll 8
    for (int e = 0; e < 32; ++e)
        s += act2[((size_t)(b * 32 + e)) * 256 + t] * wlin[t * 32 + e];
#pragma unroll
    for (int off = 32; off > 0; off >>= 1) s += __shfl_down(s, off, 64);
    __shared__ float partial[4];
    if ((t & 63) == 0) partial[t >> 6] = s;
    __syncthreads();
    if (t == 0) {
        float tot = partial[0] + partial[1] + partial[2] + partial[3] + blin[0];
        out[b] = 1.f / (1.f + expf(-tot));
    }
}

extern "C" void kernel_launch(void* const* d_in, const int* in_sizes, int n_in,
                              void* d_out, int out_size, void* d_ws, size_t ws_size,
                              hipStream_t stream) {
    const float* x    = (const float*)d_in[0];
    const float* eattr= (const float*)d_in[1];
    const float* w1   = (const float*)d_in[2];
    const float* wg   = (const float*)d_in[3];
    const float* bg   = (const float*)d_in[4];
    const float* wc1  = (const float*)d_in[5];
    const float* bc1  = (const float*)d_in[6];
    const float* wc2  = (const float*)d_in[7];
    const float* bc2  = (const float*)d_in[8];
    const float* wlin = (const float*)d_in[9];
    const float* blin = (const float*)d_in[10];
    const int*   ei   = (const int*)d_in[11];
    const int* esrc = ei;
    const int* edst = ei + N_EDGES;
    float* out = (float*)d_out;

    // workspace layout (bytes, all 16B aligned)
    char* ws = (char*)d_ws;
    float*          dinv  = (float*)(ws);                       // 262144 B
    __hip_bfloat16* WTbf  = (__hip_bfloat16*)(ws + 262144);     // 131072 B
    float*          y     = (float*)(ws + 393216);              // 33554432 B
    __hip_bfloat16* ybf   = (__hip_bfloat16*)(ws + 33947648);   // 16777216 B
    __hip_bfloat16* V     = (__hip_bfloat16*)(ws + 50724864);   // 67108864 B
    __hip_bfloat16* act1  = (__hip_bfloat16*)(ws + 117833728);  // 16777216 B
    float*          act2  = (float*)(ws + 134610944);           // 16777216 B
    __hip_bfloat16* wc1bf = (__hip_bfloat16*)(ws + 151388160);  // 2097152 B
    __hip_bfloat16* wc2bf = (__hip_bfloat16*)(ws + 153485312);  // 262144 B
    if (ws_size < (size_t)153747456) return;

    // 1) gcn_norm
    deg_init_k<<<N_NODES / 256, 256, 0, stream>>>(dinv);
    deg_acc_k<<<N_EDGES / 256, 256, 0, stream>>>(edst, eattr, dinv);
    deg_fin_k<<<N_NODES / 256, 256, 0, stream>>>(dinv);

    // 2) W_comb^T (bf16)
    wcomb_k<<<(512 * 128) / 256, 256, 0, stream>>>(w1, wg, WTbf);

    // 3) y = P x (fp32)
    y_init_k<<<(N_NODES * 32) / 256, 256, 0, stream>>>(x, dinv, y);
    y_edge_k<<<(N_EDGES * 64) / 256, 256, 0, stream>>>(esrc, edst, eattr, dinv, x, y);

    // 4) bf16 conversions
    f2b_k<<<(N_NODES * 128 / 4) / 256, 256, 0, stream>>>(y, ybf);
    f2b_k<<<(512 * 2048 / 4) / 256, 256, 0, stream>>>(wc1, wc1bf);
    f2b_k<<<(256 * 512 / 4) / 256, 256, 0, stream>>>(wc2, wc2bf);

    // 5) h2 = tanh(y @ W_comb + b_gcn) -> V (bf16, rearranged layout)
    gemm_mfma_k<2, 2><<<dim3(512 / 128, 65536 / 128), 256, 0, stream>>>(
        ybf, WTbf, bg, V, 65536, 512, 128);

    // 6) cnn1: act1 = relu(V @ wc1^T + bc1)  (16384 x 2048) x (512 x 2048)^T
    gemm_mfma_k<1, 1><<<dim3(512 / 128, 16384 / 128), 256, 0, stream>>>(
        V, wc1bf, bc1, act1, 16384, 512, 2048);

    // 7) cnn2: act2 = relu(act1 @ wc2^T + bc2)  (16384 x 512) x (256 x 512)^T
    gemm_mfma_k<1, 0><<<dim3(256 / 128, 16384 / 128), 256, 0, stream>>>(
        act1, wc2bf, bc2, act2, 16384, 256, 512);

    // 8) final linear + sigmoid
    final_k<<<BS, 256, 0, stream>>>(act2, wlin, blin, out);
}

// Round 3
// 323.112 us; speedup vs baseline: 4.2594x; 1.9355x over previous
//
#include <hip/hip_runtime.h>
#include <hip/hip_bf16.h>

#define N_NODES 65536
#define N_EDGES 524288
#define BS 512

typedef __attribute__((ext_vector_type(8))) short bf16x8;
typedef __attribute__((ext_vector_type(4))) float f32x4;

// ---------------- degree / count ----------------
__global__ void deg_init_k(float* __restrict__ deg) {
    int i = blockIdx.x * 256 + threadIdx.x;
    deg[i] = 1.0f;  // self-loop weight
}
__global__ void deg_cnt_k(const int* __restrict__ dst, const float* __restrict__ w,
                          float* __restrict__ deg, int* __restrict__ cnt) {
    int e = blockIdx.x * 256 + threadIdx.x;
    int d = dst[e];
    atomicAdd(&deg[d], w[e]);
    atomicAdd(&cnt[d], 1);
}
__global__ void deg_fin_k(float* __restrict__ deg) {
    int i = blockIdx.x * 256 + threadIdx.x;
    deg[i] = rsqrtf(deg[i]);
}

// ---------------- exclusive prefix sum of 65536 ints (single block) ------------
__global__ __launch_bounds__(1024) void scan_k(const int* __restrict__ cnt,
                                               int* __restrict__ rp) {
    __shared__ int sums[1024];
    int t = threadIdx.x;
    int base = t * 64;
    int s = 0;
#pragma unroll
    for (int i = 0; i < 64; ++i) s += cnt[base + i];
    sums[t] = s;
    __syncthreads();
    for (int d = 1; d < 1024; d <<= 1) {
        int v = (t >= d) ? sums[t - d] : 0;
        __syncthreads();
        if (t >= d) sums[t] += v;
        __syncthreads();
    }
    int run = (t == 0) ? 0 : sums[t - 1];
#pragma unroll
    for (int i = 0; i < 64; ++i) {
        rp[base + i] = run;
        run += cnt[base + i];
    }
    if (t == 1023) rp[65536] = run;
}

// ---------------- scatter edges into dst-sorted CSR order ---------------------
__global__ void scatter_k(const int* __restrict__ src, const int* __restrict__ dst,
                          const float* __restrict__ w, const float* __restrict__ dinv,
                          int* __restrict__ cursor, int* __restrict__ ssrc,
                          float* __restrict__ scoef) {
    int e = blockIdx.x * 256 + threadIdx.x;
    int s = src[e], d = dst[e];
    int pos = atomicAdd(&cursor[d], 1);
    ssrc[pos] = s;
    scoef[pos] = dinv[s] * w[e] * dinv[d];
}

// ---------------- gather SpMM: ybf[n] = bf16( P x )[n] ------------------------
// one wave per node; lane holds channels [2l, 2l+1]
__global__ __launch_bounds__(256) void gather_k(const int* __restrict__ rp,
                                                const int* __restrict__ ssrc,
                                                const float* __restrict__ scoef,
                                                const float* __restrict__ x,
                                                const float* __restrict__ dinv,
                                                __hip_bfloat16* __restrict__ ybf) {
    int n = (blockIdx.x * 256 + threadIdx.x) >> 6;
    int lane = threadIdx.x & 63;
    int beg = rp[n], end = rp[n + 1];
    float di = dinv[n];
    float2 acc;
    {
        float2 xv = *(const float2*)(x + (size_t)n * 128 + lane * 2);
        float c = di * di;
        acc.x = c * xv.x;
        acc.y = c * xv.y;
    }
    int s0 = 0;
    float c0 = 0.f;
    if (beg < end) { s0 = ssrc[beg]; c0 = scoef[beg]; }
    for (int i = beg; i < end; ++i) {
        int s1 = 0;
        float c1 = 0.f;
        if (i + 1 < end) { s1 = ssrc[i + 1]; c1 = scoef[i + 1]; }
        float2 xv = *(const float2*)(x + (size_t)s0 * 128 + lane * 2);
        acc.x += c0 * xv.x;
        acc.y += c0 * xv.y;
        s0 = s1;
        c0 = c1;
    }
    alignas(4) __hip_bfloat16 o[2] = {__float2bfloat16(acc.x), __float2bfloat16(acc.y)};
    *(unsigned int*)((unsigned short*)ybf + (size_t)n * 128 + lane * 2) =
        *(const unsigned int*)o;
}

// ---------------- W_comb^T = (w1_gcn2 @ w_gcn)^T in bf16, layout [f][c] -------
__global__ void wcomb_k(const float* __restrict__ w1, const float* __restrict__ wg,
                        __hip_bfloat16* __restrict__ WT) {
    int t = blockIdx.x * 256 + threadIdx.x;  // 512*128
    int f = t >> 7, c = t & 127;
    float s = 0.f;
#pragma unroll 8
    for (int m = 0; m < 128; ++m) s += w1[c * 128 + m] * wg[m * 512 + f];
    WT[t] = __float2bfloat16(s);
}

// ---------------- fp32 -> bf16 vectorized conversion --------------------------
__global__ void f2b_k(const float* __restrict__ in, __hip_bfloat16* __restrict__ out) {
    int i = (blockIdx.x * 256 + threadIdx.x) * 4;
    float4 v = *(const float4*)(in + i);
    alignas(8) __hip_bfloat16 tmp[4] = {__float2bfloat16(v.x), __float2bfloat16(v.y),
                                        __float2bfloat16(v.z), __float2bfloat16(v.w)};
    *(ushort4*)((unsigned short*)out + i) = *(const ushort4*)tmp;
}

// ---------------- async global -> LDS, 16B per lane ---------------------------
__device__ __forceinline__ void gll16(const void* g, void* l) {
    __builtin_amdgcn_global_load_lds(
        (const __attribute__((address_space(1))) void*)g,
        (__attribute__((address_space(3))) void*)l, 16, 0, 0);
}

// ---------------- bf16 MFMA GEMM: C = act(A @ B^T + bias) ---------------------
// A: M x K bf16 row-major. B: N x K bf16 row-major ((out,in) weights).
// ACT: 0 none, 1 relu, 2 tanh.
// OUT_MODE: 0 fp32 row-major, 1 bf16 row-major, 2 bf16 with rearrange-permute.
// 128x128 tile, BK=32, 4 waves (2x2), each wave 64x64 via 4x4 16x16x32 frags.
template <int ACT, int OUT_MODE>
__global__ __launch_bounds__(256) void gemm_mfma_k(
    const __hip_bfloat16* __restrict__ A, const __hip_bfloat16* __restrict__ B,
    const float* __restrict__ bias, void* __restrict__ Cout,
    int M, int N, int K) {
    __shared__ char lds[16384];  // A tile 8KB | B tile 8KB
    char* ldsA = lds;
    char* ldsB = lds + 8192;

    const int tid = threadIdx.x;
    const int lane = tid & 63, wid = tid >> 6;
    const int bm = blockIdx.y * 128, bn = blockIdx.x * 128;
    const int wr = wid >> 1, wc = wid & 1;

    const int srow = wid * 16 + (lane >> 2);
    const int skcol = (lane & 3) * 8;
    const __hip_bfloat16* Abase = A + (size_t)(bm + srow) * K + skcol;
    const __hip_bfloat16* Bbase = B + (size_t)(bn + srow) * K + skcol;
    const int ldso = wid * 1024;

    f32x4 acc[4][4] = {};

    const int lrow = lane & 15;
    const int lkb = (lane >> 4) * 16;

    for (int kt = 0; kt < K; kt += 32) {
        gll16(Abase + kt,                  ldsA + ldso);
        gll16(Abase + kt + (size_t)64 * K, ldsA + 4096 + ldso);
        gll16(Bbase + kt,                  ldsB + ldso);
        gll16(Bbase + kt + (size_t)64 * K, ldsB + 4096 + ldso);
        __syncthreads();

        bf16x8 af[4], bfr[4];
#pragma unroll
        for (int i = 0; i < 4; ++i)
            af[i] = *(const bf16x8*)(ldsA + (wr * 64 + i * 16 + lrow) * 64 + lkb);
#pragma unroll
        for (int j = 0; j < 4; ++j)
            bfr[j] = *(const bf16x8*)(ldsB + (wc * 64 + j * 16 + lrow) * 64 + lkb);
#pragma unroll
        for (int i = 0; i < 4; ++i)
#pragma unroll
            for (int j = 0; j < 4; ++j)
                acc[i][j] = __builtin_amdgcn_mfma_f32_16x16x32_bf16(
                    af[i], bfr[j], acc[i][j], 0, 0, 0);
        __syncthreads();
    }

    const int crow0 = wr * 64 + (lane >> 4) * 4;
    const int ccol0 = wc * 64 + (lane & 15);
#pragma unroll
    for (int i = 0; i < 4; ++i) {
#pragma unroll
        for (int j = 0; j < 4; ++j) {
            int col = bn + ccol0 + j * 16;
            float bv = bias[col];
#pragma unroll
            for (int r = 0; r < 4; ++r) {
                int row = bm + crow0 + i * 16 + r;
                float v = acc[i][j][r] + bv;
                if (ACT == 1) v = fmaxf(v, 0.f);
                if (ACT == 2) v = tanhf(v);
                if (OUT_MODE == 0) {
                    ((float*)Cout)[(size_t)row * N + col] = v;
                } else if (OUT_MODE == 1) {
                    ((__hip_bfloat16*)Cout)[(size_t)row * N + col] = __float2bfloat16(v);
                } else {
                    size_t prow = (size_t)(((row >> 7) << 5) | (row & 31));
                    size_t idx = prow * 2048 + (size_t)(((row >> 5) & 3) * 512 + col);
                    ((__hip_bfloat16*)Cout)[idx] = __float2bfloat16(v);
                }
            }
        }
    }
}

// ---------------- final: out[b] = sigmoid(sum act2[(b*32+e), p] * wlin[p*32+e]) ----
__global__ __launch_bounds__(256) void final_k(const float* __restrict__ act2,
                                               const float* __restrict__ wlin,
                                               const float* __restrict__ blin,
                                               float* __restrict__ out) {
    int b = blockIdx.x;
    int t = threadIdx.x;
    float s = 0.f;
#pragma unroll 8
    for (int e = 0; e < 32; ++e)
        s += act2[((size_t)(b * 32 + e)) * 256 + t] * wlin[t * 32 + e];
#pragma unroll
    for (int off = 32; off > 0; off >>= 1) s += __shfl_down(s, off, 64);
    __shared__ float partial[4];
    if ((t & 63) == 0) partial[t >> 6] = s;
    __syncthreads();
    if (t == 0) {
        float tot = partial[0] + partial[1] + partial[2] + partial[3] + blin[0];
        out[b] = 1.f / (1.f + expf(-tot));
    }
}

extern "C" void kernel_launch(void* const* d_in, const int* in_sizes, int n_in,
                              void* d_out, int out_size, void* d_ws, size_t ws_size,
                              hipStream_t stream) {
    const float* x    = (const float*)d_in[0];
    const float* eattr= (const float*)d_in[1];
    const float* w1   = (const float*)d_in[2];
    const float* wg   = (const float*)d_in[3];
    const float* bg   = (const float*)d_in[4];
    const float* wc1  = (const float*)d_in[5];
    const float* bc1  = (const float*)d_in[6];
    const float* wc2  = (const float*)d_in[7];
    const float* bc2  = (const float*)d_in[8];
    const float* wlin = (const float*)d_in[9];
    const float* blin = (const float*)d_in[10];
    const int*   ei   = (const int*)d_in[11];
    const int* esrc = ei;
    const int* edst = ei + N_EDGES;
    float* out = (float*)d_out;

    // workspace layout (bytes, 16B aligned)
    char* ws = (char*)d_ws;
    float*          dinv   = (float*)(ws + 0);          // 262144
    int*            cnt    = (int*)(ws + 262144);       // 262144
    int*            rp     = (int*)(ws + 524288);       // 262160 (65537 ints)
    int*            cursor = (int*)(ws + 786688);       // 262144
    int*            ssrc   = (int*)(ws + 1048832);      // 2097152
    float*          scoef  = (float*)(ws + 3145984);    // 2097152
    __hip_bfloat16* WTbf   = (__hip_bfloat16*)(ws + 5243136);   // 131072
    __hip_bfloat16* ybf    = (__hip_bfloat16*)(ws + 5374208);   // 16777216
    __hip_bfloat16* V      = (__hip_bfloat16*)(ws + 22151424);  // 67108864
    __hip_bfloat16* act1   = (__hip_bfloat16*)(ws + 89260288);  // 16777216
    float*          act2   = (float*)(ws + 106037504);  // 16777216
    __hip_bfloat16* wc1bf  = (__hip_bfloat16*)(ws + 122814720); // 2097152
    __hip_bfloat16* wc2bf  = (__hip_bfloat16*)(ws + 124911872); // 262144
    if (ws_size < (size_t)125174016) return;

    // 1) degree + per-node edge counts
    hipMemsetAsync(cnt, 0, 262144, stream);
    deg_init_k<<<N_NODES / 256, 256, 0, stream>>>(dinv);
    deg_cnt_k<<<N_EDGES / 256, 256, 0, stream>>>(edst, eattr, dinv, cnt);
    deg_fin_k<<<N_NODES / 256, 256, 0, stream>>>(dinv);

    // 2) CSR build: row_ptr + dst-sorted (src, coef)
    scan_k<<<1, 1024, 0, stream>>>(cnt, rp);
    hipMemcpyAsync(cursor, rp, 262144, hipMemcpyDeviceToDevice, stream);
    scatter_k<<<N_EDGES / 256, 256, 0, stream>>>(esrc, edst, eattr, dinv,
                                                 cursor, ssrc, scoef);

    // 3) gather SpMM -> ybf (bf16)
    gather_k<<<N_NODES / 4, 256, 0, stream>>>(rp, ssrc, scoef, x, dinv, ybf);

    // 4) weights: W_comb^T (bf16) + bf16 conversions
    wcomb_k<<<(512 * 128) / 256, 256, 0, stream>>>(w1, wg, WTbf);
    f2b_k<<<(512 * 2048 / 4) / 256, 256, 0, stream>>>(wc1, wc1bf);
    f2b_k<<<(256 * 512 / 4) / 256, 256, 0, stream>>>(wc2, wc2bf);

    // 5) h2 = tanh(y @ W_comb + b_gcn) -> V (bf16, rearranged layout)
    gemm_mfma_k<2, 2><<<dim3(512 / 128, 65536 / 128), 256, 0, stream>>>(
        ybf, WTbf, bg, V, 65536, 512, 128);

    // 6) cnn1: act1 = relu(V @ wc1^T + bc1)  (16384 x 2048) x (512 x 2048)^T
    gemm_mfma_k<1, 1><<<dim3(512 / 128, 16384 / 128), 256, 0, stream>>>(
        V, wc1bf, bc1, act1, 16384, 512, 2048);

    // 7) cnn2: act2 = relu(act1 @ wc2^T + bc2)  (16384 x 512) x (256 x 512)^T
    gemm_mfma_k<1, 0><<<dim3(256 / 128, 16384 / 128), 256, 0, stream>>>(
        act1, wc2bf, bc2, act2, 16384, 256, 512);

    // 8) final linear + sigmoid
    final_k<<<BS, 256, 0, stream>>>(act2, wlin, blin, out);
}